// Round 15
// baseline (716.253 us; speedup 1.0000x reference)
//
#include <hip/hip_runtime.h>
#include <math.h>

#define NA 16384
#define NE 262144

// workspace layout in floats
#define SI_OFF   0                         // [NA][3]
#define SB_OFF   (NA*3)                    // [3][NA][96]  (j-side, streamed hot)
#define NM_OFF   (SB_OFF + 3*NA*96)        // [NA][32][16]  (13 used, pad 16)
#define SRBF_OFF (NM_OFF + NA*512)         // [NA][8] per-atom spin basis (512KB)
#define RWT_OFF  (SRBF_OFF + NA*8)         // [3][96][8]  rbf_w transposed
#define SWT_OFF  (RWT_OFF + 3*96*8)        // [3][96][8]  srbf_w transposed
#define WS_FLOATS (SWT_OFF + 3*96*8)
// int region (reuse ws, cast to int*)
#define HIST_OFF (WS_FLOATS)               // [NA] ints
#define PERM_OFF (HIST_OFF + NA)           // [NE] ints

__global__ __launch_bounds__(256) void repack_rw_k(const float* __restrict__ rbf_w,
                                                   const float* __restrict__ srbf_w,
                                                   float* __restrict__ ws) {
    int t = blockIdx.x * 256 + threadIdx.x;       // over 2*3*96*8 = 4608
    if (t >= 4608) return;
    int u = (t >= 2304) ? t - 2304 : t;
    int k = u & 7;
    int c = (u >> 3) % 96;
    int w = u / 768;
    if (t < 2304)
        ws[RWT_OFF + u] = rbf_w[w * 768 + k * 96 + c];
    else
        ws[SWT_OFF + u] = srbf_w[w * 768 + k * 96 + c];
}

__global__ __launch_bounds__(256) void hist_zero_k(int* __restrict__ hist) {
    int t = blockIdx.x * 256 + threadIdx.x;
    if (t < NA) hist[t] = 0;
}

__global__ __launch_bounds__(256) void hist_k(const int* __restrict__ idx_j,
                                              int* __restrict__ hist) {
    int e = blockIdx.x * 256 + threadIdx.x;
    if (e < NE) atomicAdd(&hist[idx_j[e]], 1);
}

// single block, 256 threads, 64 entries each: counts -> exclusive offsets
__global__ __launch_bounds__(256) void scan_k(int* __restrict__ hist) {
    __shared__ int sums[256];
    int t = threadIdx.x;
    int lo = t * 64;
    int s = 0;
    for (int k = 0; k < 64; ++k) s += hist[lo + k];
    sums[t] = s;
    __syncthreads();
    for (int off = 1; off < 256; off <<= 1) {
        int v = (t >= off) ? sums[t - off] : 0;
        __syncthreads();
        sums[t] += v;
        __syncthreads();
    }
    int ex = sums[t] - s;                 // exclusive prefix of this chunk
    for (int k = 0; k < 64; ++k) {
        int c = hist[lo + k];
        hist[lo + k] = ex;
        ex += c;
    }
}

__global__ __launch_bounds__(256) void scatter_k(const int* __restrict__ idx_j,
                                                 int* __restrict__ hist,
                                                 int* __restrict__ perm) {
    int e = blockIdx.x * 256 + threadIdx.x;
    if (e < NE) {
        int pos = atomicAdd(&hist[idx_j[e]], 1);
        perm[pos] = e;
    }
}

__global__ __launch_bounds__(256) void atom_prep_k(
    const float* __restrict__ node0, const float* __restrict__ node1,
    const float* __restrict__ node2, const float* __restrict__ spin,
    const float* __restrict__ srbf_w, const float* __restrict__ srbf_b,
    const float* __restrict__ U_w, float* __restrict__ ws)
{
    const int wave = threadIdx.x >> 6;
    const int lane = threadIdx.x & 63;
    const int a = blockIdx.x * 4 + wave;
    if (a >= NA) return;

    float sx = spin[a*3+0], sy = spin[a*3+1], sz = spin[a*3+2];
    float mi = sqrtf(sx*sx + sy*sy + sz*sz + 1e-12f);
    float inv = 1.0f / mi;
    if (lane < 3) ws[SI_OFF + a*3 + lane] = spin[a*3 + lane] * inv;

    float srbf[8];
    #pragma unroll
    for (int k = 0; k < 8; ++k) {
        float d = mi - (float)k * (3.0f / 7.0f);
        srbf[k] = expf(-4.0f * d * d);
    }
    // store the per-atom basis (the i-side random gather reads THIS, 32B,
    // from a 512KB L2-resident table instead of the 19MB sb table)
    if (lane == 0) {
        float* p = ws + SRBF_OFF + (size_t)a*8;
        *(float4*)(p + 0) = make_float4(srbf[0], srbf[1], srbf[2], srbf[3]);
        *(float4*)(p + 4) = make_float4(srbf[4], srbf[5], srbf[6], srbf[7]);
    }

    #pragma unroll
    for (int w = 0; w < 3; ++w) {
        #pragma unroll
        for (int rep = 0; rep < 2; ++rep) {
            int c = rep * 64 + lane;
            if (c < 96) {
                float acc = srbf_b[w*96 + c];
                #pragma unroll
                for (int k = 0; k < 8; ++k)
                    acc = fmaf(srbf[k], srbf_w[w*768 + k*96 + c], acc);
                ws[SB_OFF + ((size_t)w*NA + a)*96 + c] = acc;
            }
        }
    }

    const int o = lane & 31;
    const int h = lane >> 5;
    float acc[13];
    #pragma unroll
    for (int sp = 0; sp < 13; ++sp) acc[sp] = 0.0f;

    for (int cc = 0; cc < 16; ++cc) {
        int c = h * 16 + cc;
        float f0 = node0[a*32 + c];
        float u0 = U_w[0*1024 + c*32 + o];
        float u1 = U_w[1*1024 + c*32 + o];
        float u2 = U_w[2*1024 + c*32 + o];
        acc[0] = fmaf(f0, u0, acc[0]);
        #pragma unroll
        for (int jj = 0; jj < 3; ++jj)
            acc[1+jj] = fmaf(node1[a*96 + c*3 + jj], u1, acc[1+jj]);
        #pragma unroll
        for (int ij = 0; ij < 9; ++ij)
            acc[4+ij] = fmaf(node2[a*288 + c*9 + ij], u2, acc[4+ij]);
    }
    #pragma unroll
    for (int sp = 0; sp < 13; ++sp)
        acc[sp] += __shfl_xor(acc[sp], 32);

    if (h == 0) {
        float* p = ws + NM_OFF + (size_t)a*512 + o*16;
        *(float4*)(p + 0)  = make_float4(acc[0], acc[1], acc[2], acc[3]);
        *(float4*)(p + 4)  = make_float4(acc[4], acc[5], acc[6], acc[7]);
        *(float4*)(p + 8)  = make_float4(acc[8], acc[9], acc[10], acc[11]);
        *(float4*)(p + 12) = make_float4(acc[12], 0.f, 0.f, 0.f);
    }
}

// FUSED edge kernel, perm (j-sorted) order (r14 structure).
// r15 change: the i-side no longer gathers the 1152B sb[i] region (the only
// randomly-REUSED stream; its L3 re-fetch under write pressure was ~100MB of
// r14's 155MB FETCH). Instead gather srbf_i[8] (32B from a 512KB L2-resident
// table) and reconstruct sbi_c with 8 FMA per c from LDS-staged swt
// (9.2KB; r10 failed doing this via VMEM uniform reads, r11 failed staging
// the 37KB V_w too -- this stages ONLY swt). FMA order matches atom_prep
// exactly and srbf values are the stored ones -> bit-identical results.
__global__ __launch_bounds__(256) void edge_fused_k(
    const float* __restrict__ coord, const int* __restrict__ idx_i,
    const int* __restrict__ idx_j, const float* __restrict__ rbf_b,
    const float* __restrict__ srbf_b,
    const float* __restrict__ V_w, const float* __restrict__ ws,
    const int* __restrict__ perm, float* __restrict__ out)
{
    __shared__ float hand[4][8][104];          // [wave][slot][100 + 4 pad]
    __shared__ float obuf[4][8][132];          // [wave][slot][96 p1 + 32 p0 + 4]
    __shared__ float lds_swt[3*96*8];          // 9216 B
    const int lane = threadIdx.x & 63;
    const int wv   = threadIdx.x >> 6;

    for (int t0 = threadIdx.x; t0 < 3*96*8; t0 += 256)
        lds_swt[t0] = ws[SWT_OFF + t0];
    __syncthreads();   // once per block, before any loads of consequence

    const int t = blockIdx.x * 256 + threadIdx.x;
    const int e = perm[t];                 // j-sorted
    const int i = idx_i[e];
    const int j = idx_j[e];

    float rx = coord[j*3+0] - coord[i*3+0];
    float ry = coord[j*3+1] - coord[i*3+1];
    float rz = coord[j*3+2] - coord[i*3+2];
    float d2 = rx*rx + ry*ry + rz*rz + 1e-12f;
    float dij = sqrtf(d2);
    float invd = 1.0f / dij;
    float ux = rx*invd, uy = ry*invd, uz = rz*invd;

    float tt = fminf(dij * 0.2f, 1.0f);
    float fc = 0.5f * (cosf(3.14159265358979323846f * tt) + 1.0f);
    float rbf[8];
    #pragma unroll
    for (int k = 0; k < 8; ++k) {
        float d = dij - (float)k * (5.0f / 7.0f);
        rbf[k] = expf(-4.0f * d * d) * fc;
    }

    // i-side basis: 32B gather from the 512KB L2-resident srbf table
    const float* sp_ = ws + SRBF_OFF + (size_t)i*8;
    float4 sb0 = *(const float4*)(sp_ + 0);
    float4 sb1 = *(const float4*)(sp_ + 4);
    float srbf_i[8] = {sb0.x, sb0.y, sb0.z, sb0.w,
                       sb1.x, sb1.y, sb1.z, sb1.w};

    const float* si = ws + SI_OFF;
    float sij = si[i*3+0]*si[j*3+0] + si[i*3+1]*si[j*3+1] + si[i*3+2]*si[j*3+2];
    float cheb1 = sij;
    float cheb2 = 2.0f * sij * sij - 1.0f;

    float sall[3][32];

    #pragma unroll
    for (int w = 0; w < 3; ++w) {
        const float* sbj = ws + SB_OFF + ((size_t)w*NA + j)*96;
        const float* rwt = ws + RWT_OFF + w*768;   // [96][8] (uniform/scalar)
        const float* swt = lds_swt + w*768;        // [96][8] in LDS
        const float* rbb = rbf_b + w*96;
        const float* sbb = srbf_b + w*96;
        const float* vw  = V_w + w*3072;           // [96][32]

        float s[32];
        #pragma unroll
        for (int o = 0; o < 32; ++o) s[o] = 0.0f;

        #pragma unroll
        for (int tb = 0; tb < 3; ++tb) {
            float chb = (tb == 0) ? 1.0f : ((tb == 1) ? cheb1 : cheb2);
            #pragma unroll 4
            for (int cc = 0; cc < 8; ++cc) {
                int c0 = tb*32 + cc*4;
                float4 vj = *(const float4*)(sbj + c0);
                float sbjv[4] = {vj.x, vj.y, vj.z, vj.w};
                #pragma unroll
                for (int q = 0; q < 4; ++q) {
                    int c = c0 + q;
                    float rm = rbb[c];
                    #pragma unroll
                    for (int k = 0; k < 8; ++k)
                        rm = fmaf(rbf[k], rwt[c*8 + k], rm);
                    // reconstruct sbi_c: identical FMA order to atom_prep
                    float sbi_c = sbb[c];
                    #pragma unroll
                    for (int k = 0; k < 8; ++k)
                        sbi_c = fmaf(srbf_i[k], swt[c*8 + k], sbi_c);
                    float g = rm * (sbi_c * sbjv[q]) * chb;
                    const float* vc = vw + c*32;
                    #pragma unroll
                    for (int o = 0; o < 32; ++o)
                        s[o] = fmaf(vc[o], g, s[o]);
                }
            }
        }
        #pragma unroll
        for (int o = 0; o < 32; ++o) sall[w][o] = s[o];
    }

    // ---- Phase 2: 8 rounds of wave-local 1->8 transpose + epilogue ----
    const int g = lane >> 3;
    const int q = lane & 7;
    float* myslot = &hand[wv][lane & 7][0];
    const float* gslot = &hand[wv][g][0];
    float* myob = &obuf[wv][g][0];

    #pragma unroll 1
    for (int r = 0; r < 8; ++r) {
        if ((lane >> 3) == r) {
            #pragma unroll
            for (int w = 0; w < 3; ++w)
                #pragma unroll
                for (int k = 0; k < 8; ++k)
                    *(float4*)(myslot + w*32 + k*4) =
                        make_float4(sall[w][k*4+0], sall[w][k*4+1],
                                    sall[w][k*4+2], sall[w][k*4+3]);
            *(float4*)(myslot + 96) = make_float4(ux, uy, uz, 0.0f);
        }
        __builtin_amdgcn_wave_barrier();   // wave-level scheduling fence

        const int sl  = r*8 + g;
        const int e_r = __shfl(e, sl);
        const int j_r = __shfl(j, sl);

        float4 sv0 = *(const float4*)(gslot + 0  + q*4);
        float4 sv1 = *(const float4*)(gslot + 32 + q*4);
        float4 sv2 = *(const float4*)(gslot + 64 + q*4);
        float4 uu  = *(const float4*)(gslot + 96);
        float uxr = uu.x, uyr = uu.y, uzr = uu.z;
        float c0[4] = {sv0.x, sv0.y, sv0.z, sv0.w};
        float c1[4] = {sv1.x, sv1.y, sv1.z, sv1.w};
        float c2[4] = {sv2.x, sv2.y, sv2.z, sv2.w};

        const float* nmj = ws + NM_OFF + (size_t)j_r*512 + q*64;

        float r0[4], r1[12], r2[36];
        #pragma unroll
        for (int oo = 0; oo < 4; ++oo) {
            const float* nmo = nmj + oo*16;
            float4 va  = *(const float4*)(nmo + 0);
            float4 vb  = *(const float4*)(nmo + 4);
            float4 vc4 = *(const float4*)(nmo + 8);
            float nd   = nmo[12];
            float n0 = va.x, n1x = va.y, n1y = va.z, n1z = va.w;
            float t00 = vb.x, t01 = vb.y, t02 = vb.z, t10 = vb.w;
            float t11 = vc4.x, t12 = vc4.y, t20 = vc4.z, t21 = vc4.w, t22 = nd;
            float s0 = c0[oo], s1 = c1[oo], s2 = c2[oo];

            float d1 = n1x*uxr + n1y*uyr + n1z*uzr;
            float m0 = t00*uxr + t01*uyr + t02*uzr;
            float m1 = t10*uxr + t11*uyr + t12*uzr;
            float m2 = t20*uxr + t21*uyr + t22*uzr;
            float qq = m0*uxr + m1*uyr + m2*uzr;

            r0[oo] = n0*s0 + d1*s1 + qq*s2;

            float w1 = n0*s1 + s2*d1;
            r1[oo*3+0] = w1*uxr + n1x*s0 + s1*m0;
            r1[oo*3+1] = w1*uyr + n1y*s0 + s1*m1;
            r1[oo*3+2] = w1*uzr + n1z*s0 + s1*m2;

            float n0s2 = n0*s2;
            float a0 = uxr*n0s2 + s1*n1x + s2*m0;
            float a1 = uyr*n0s2 + s1*n1y + s2*m1;
            float a2 = uzr*n0s2 + s1*n1z + s2*m2;
            r2[oo*9+0] = a0*uxr + s0*t00;
            r2[oo*9+1] = a0*uyr + s0*t01;
            r2[oo*9+2] = a0*uzr + s0*t02;
            r2[oo*9+3] = a1*uxr + s0*t10;
            r2[oo*9+4] = a1*uyr + s0*t11;
            r2[oo*9+5] = a1*uzr + s0*t12;
            r2[oo*9+6] = a2*uxr + s0*t20;
            r2[oo*9+7] = a2*uyr + s0*t21;
            r2[oo*9+8] = a2*uzr + s0*t22;
        }

        // p2: direct stores (9-instruction tight burst combines in L2)
        float* p2 = out + (size_t)NE*128 + (size_t)e_r*288 + q*36;
        #pragma unroll
        for (int k = 0; k < 9; ++k)
            *(float4*)(p2 + k*4) =
                make_float4(r2[k*4+0], r2[k*4+1], r2[k*4+2], r2[k*4+3]);

        // p1/p0: stage in per-wave LDS (o-major layout = output layout)
        #pragma unroll
        for (int k = 0; k < 3; ++k)
            *(float4*)(myob + q*12 + k*4) =
                make_float4(r1[k*4+0], r1[k*4+1], r1[k*4+2], r1[k*4+3]);
        *(float4*)(myob + 96 + q*4) =
            make_float4(r0[0], r0[1], r0[2], r0[3]);
        __builtin_amdgcn_wave_barrier();

        // cooperative full-line store: group g streams edge-slot g's p1/p0;
        // each instruction = 8 lanes x 16B contiguous = one full 128B line.
        {
            const float* ob = &obuf[wv][g][0];
            float* d1 = out + (size_t)NE*32 + (size_t)e_r*96;
            #pragma unroll
            for (int k = 0; k < 3; ++k) {
                float4 v = *(const float4*)(ob + k*32 + q*4);
                *(float4*)(d1 + k*32 + q*4) = v;
            }
            float4 v0 = *(const float4*)(ob + 96 + q*4);
            *(float4*)(out + (size_t)e_r*32 + q*4) = v0;
        }

        __builtin_amdgcn_wave_barrier();   // keep next round's slot writes
                                           // behind this round's slot reads
    }
}

extern "C" void kernel_launch(void* const* d_in, const int* in_sizes, int n_in,
                              void* d_out, int out_size, void* d_ws, size_t ws_size,
                              hipStream_t stream) {
    const float* node0  = (const float*)d_in[0];
    const float* node1  = (const float*)d_in[1];
    const float* node2  = (const float*)d_in[2];
    const float* coord  = (const float*)d_in[3];
    const float* spin   = (const float*)d_in[4];
    const int*   idx_i  = (const int*)d_in[5];
    const int*   idx_j  = (const int*)d_in[6];
    const float* rbf_w  = (const float*)d_in[7];
    const float* rbf_b  = (const float*)d_in[8];
    const float* srbf_w = (const float*)d_in[9];
    const float* srbf_b = (const float*)d_in[10];
    const float* U_w    = (const float*)d_in[11];
    const float* V_w    = (const float*)d_in[12];
    float* out = (float*)d_out;
    float* ws  = (float*)d_ws;
    int*   wsi = (int*)d_ws;
    int*   hist = wsi + HIST_OFF;
    int*   perm = wsi + PERM_OFF;

    repack_rw_k<<<(4608 + 255) / 256, 256, 0, stream>>>(rbf_w, srbf_w, ws);
    atom_prep_k<<<NA / 4, 256, 0, stream>>>(node0, node1, node2, spin,
                                            srbf_w, srbf_b, U_w, ws);
    hist_zero_k<<<NA / 256, 256, 0, stream>>>(hist);
    hist_k<<<NE / 256, 256, 0, stream>>>(idx_j, hist);
    scan_k<<<1, 256, 0, stream>>>(hist);
    scatter_k<<<NE / 256, 256, 0, stream>>>(idx_j, hist, perm);
    edge_fused_k<<<NE / 256, 256, 0, stream>>>(coord, idx_i, idx_j, rbf_b,
                                               srbf_b, V_w, ws, perm, out);
}

// Round 16
// 432.309 us; speedup vs baseline: 1.6568x; 1.6568x over previous
//
#include <hip/hip_runtime.h>
#include <math.h>

#define NA 16384
#define NE 262144

// workspace layout in floats
#define SI_OFF   0                         // [NA][3]
#define SB_OFF   (NA*3)                    // [3][NA][96]
#define NM_OFF   (SB_OFF + 3*NA*96)        // [NA][32][16]  (13 used, pad 16)
#define RWT_OFF  (NM_OFF + NA*512)         // [3][96][8]  rbf_w transposed
#define WS_FLOATS (RWT_OFF + 3*96*8)
// int region (reuse ws, cast to int*)
#define HIST_OFF (WS_FLOATS)               // [NA] ints
#define PERM_OFF (HIST_OFF + NA)           // [NE] ints

__global__ __launch_bounds__(256) void repack_rw_k(const float* __restrict__ rbf_w,
                                                   float* __restrict__ ws) {
    int t = blockIdx.x * 256 + threadIdx.x;       // over 3*96*8 = 2304
    if (t >= 2304) return;
    int k = t & 7;
    int c = (t >> 3) % 96;
    int w = t / 768;
    ws[RWT_OFF + t] = rbf_w[w * 768 + k * 96 + c];
}

__global__ __launch_bounds__(256) void hist_zero_k(int* __restrict__ hist) {
    int t = blockIdx.x * 256 + threadIdx.x;
    if (t < NA) hist[t] = 0;
}

__global__ __launch_bounds__(256) void hist_k(const int* __restrict__ idx_j,
                                              int* __restrict__ hist) {
    int e = blockIdx.x * 256 + threadIdx.x;
    if (e < NE) atomicAdd(&hist[idx_j[e]], 1);
}

// single block, 256 threads, 64 entries each: counts -> exclusive offsets
__global__ __launch_bounds__(256) void scan_k(int* __restrict__ hist) {
    __shared__ int sums[256];
    int t = threadIdx.x;
    int lo = t * 64;
    int s = 0;
    for (int k = 0; k < 64; ++k) s += hist[lo + k];
    sums[t] = s;
    __syncthreads();
    for (int off = 1; off < 256; off <<= 1) {
        int v = (t >= off) ? sums[t - off] : 0;
        __syncthreads();
        sums[t] += v;
        __syncthreads();
    }
    int ex = sums[t] - s;                 // exclusive prefix of this chunk
    for (int k = 0; k < 64; ++k) {
        int c = hist[lo + k];
        hist[lo + k] = ex;
        ex += c;
    }
}

__global__ __launch_bounds__(256) void scatter_k(const int* __restrict__ idx_j,
                                                 int* __restrict__ hist,
                                                 int* __restrict__ perm) {
    int e = blockIdx.x * 256 + threadIdx.x;
    if (e < NE) {
        int pos = atomicAdd(&hist[idx_j[e]], 1);
        perm[pos] = e;
    }
}

__global__ __launch_bounds__(256) void atom_prep_k(
    const float* __restrict__ node0, const float* __restrict__ node1,
    const float* __restrict__ node2, const float* __restrict__ spin,
    const float* __restrict__ srbf_w, const float* __restrict__ srbf_b,
    const float* __restrict__ U_w, float* __restrict__ ws)
{
    const int wave = threadIdx.x >> 6;
    const int lane = threadIdx.x & 63;
    const int a = blockIdx.x * 4 + wave;
    if (a >= NA) return;

    float sx = spin[a*3+0], sy = spin[a*3+1], sz = spin[a*3+2];
    float mi = sqrtf(sx*sx + sy*sy + sz*sz + 1e-12f);
    float inv = 1.0f / mi;
    if (lane < 3) ws[SI_OFF + a*3 + lane] = spin[a*3 + lane] * inv;

    float srbf[8];
    #pragma unroll
    for (int k = 0; k < 8; ++k) {
        float d = mi - (float)k * (3.0f / 7.0f);
        srbf[k] = expf(-4.0f * d * d);
    }

    #pragma unroll
    for (int w = 0; w < 3; ++w) {
        #pragma unroll
        for (int rep = 0; rep < 2; ++rep) {
            int c = rep * 64 + lane;
            if (c < 96) {
                float acc = srbf_b[w*96 + c];
                #pragma unroll
                for (int k = 0; k < 8; ++k)
                    acc = fmaf(srbf[k], srbf_w[w*768 + k*96 + c], acc);
                ws[SB_OFF + ((size_t)w*NA + a)*96 + c] = acc;
            }
        }
    }

    const int o = lane & 31;
    const int h = lane >> 5;
    float acc[13];
    #pragma unroll
    for (int sp = 0; sp < 13; ++sp) acc[sp] = 0.0f;

    for (int cc = 0; cc < 16; ++cc) {
        int c = h * 16 + cc;
        float f0 = node0[a*32 + c];
        float u0 = U_w[0*1024 + c*32 + o];
        float u1 = U_w[1*1024 + c*32 + o];
        float u2 = U_w[2*1024 + c*32 + o];
        acc[0] = fmaf(f0, u0, acc[0]);
        #pragma unroll
        for (int jj = 0; jj < 3; ++jj)
            acc[1+jj] = fmaf(node1[a*96 + c*3 + jj], u1, acc[1+jj]);
        #pragma unroll
        for (int ij = 0; ij < 9; ++ij)
            acc[4+ij] = fmaf(node2[a*288 + c*9 + ij], u2, acc[4+ij]);
    }
    #pragma unroll
    for (int sp = 0; sp < 13; ++sp)
        acc[sp] += __shfl_xor(acc[sp], 32);

    if (h == 0) {
        float* p = ws + NM_OFF + (size_t)a*512 + o*16;
        *(float4*)(p + 0)  = make_float4(acc[0], acc[1], acc[2], acc[3]);
        *(float4*)(p + 4)  = make_float4(acc[4], acc[5], acc[6], acc[7]);
        *(float4*)(p + 8)  = make_float4(acc[8], acc[9], acc[10], acc[11]);
        *(float4*)(p + 12) = make_float4(acc[12], 0.f, 0.f, 0.f);
    }
}

// FUSED edge kernel, perm (j-sorted) order (r13 structure + r14 p1/p0
// LDS re-transpose). This is the measured-best configuration (433.7 us):
// - Phase 1 (1 thread/edge): s[3][32] in registers; sbj/nm j-hot; sbi is
//   the single cold scattered read stream.
// - Phase 2 (8 rounds of wave-local 1->8 transpose): full-line stores for
//   all three output regions; p2 direct (tight burst combines), p1/p0 via
//   per-wave LDS re-transpose (one full 128B line per store instruction).
// VGPR=120 stays under the 128-VGPR occupancy cliff (r15 crossed it at 132
// and halved waves/CU -> 700 us). Do not add register pressure here.
__global__ __launch_bounds__(256) void edge_fused_k(
    const float* __restrict__ coord, const int* __restrict__ idx_i,
    const int* __restrict__ idx_j, const float* __restrict__ rbf_b,
    const float* __restrict__ V_w, const float* __restrict__ ws,
    const int* __restrict__ perm, float* __restrict__ out)
{
    __shared__ float hand[4][8][104];          // [wave][slot][100 + 4 pad]
    __shared__ float obuf[4][8][132];          // [wave][slot][96 p1 + 32 p0 + 4]
    const int lane = threadIdx.x & 63;
    const int wv   = threadIdx.x >> 6;
    const int t = blockIdx.x * 256 + threadIdx.x;
    const int e = perm[t];                 // j-sorted
    const int i = idx_i[e];
    const int j = idx_j[e];

    float rx = coord[j*3+0] - coord[i*3+0];
    float ry = coord[j*3+1] - coord[i*3+1];
    float rz = coord[j*3+2] - coord[i*3+2];
    float d2 = rx*rx + ry*ry + rz*rz + 1e-12f;
    float dij = sqrtf(d2);
    float invd = 1.0f / dij;
    float ux = rx*invd, uy = ry*invd, uz = rz*invd;

    float tt = fminf(dij * 0.2f, 1.0f);
    float fc = 0.5f * (cosf(3.14159265358979323846f * tt) + 1.0f);
    float rbf[8];
    #pragma unroll
    for (int k = 0; k < 8; ++k) {
        float d = dij - (float)k * (5.0f / 7.0f);
        rbf[k] = expf(-4.0f * d * d) * fc;
    }

    const float* si = ws + SI_OFF;
    float sij = si[i*3+0]*si[j*3+0] + si[i*3+1]*si[j*3+1] + si[i*3+2]*si[j*3+2];
    float cheb1 = sij;
    float cheb2 = 2.0f * sij * sij - 1.0f;

    float sall[3][32];

    #pragma unroll
    for (int w = 0; w < 3; ++w) {
        const float* sbi = ws + SB_OFF + ((size_t)w*NA + i)*96;
        const float* sbj = ws + SB_OFF + ((size_t)w*NA + j)*96;
        const float* rwt = ws + RWT_OFF + w*768;   // [96][8]
        const float* rbb = rbf_b + w*96;
        const float* vw  = V_w + w*3072;           // [96][32]

        float s[32];
        #pragma unroll
        for (int o = 0; o < 32; ++o) s[o] = 0.0f;

        #pragma unroll
        for (int tb = 0; tb < 3; ++tb) {
            float chb = (tb == 0) ? 1.0f : ((tb == 1) ? cheb1 : cheb2);
            #pragma unroll 4
            for (int cc = 0; cc < 8; ++cc) {
                int c0 = tb*32 + cc*4;
                float4 vi = *(const float4*)(sbi + c0);
                float4 vj = *(const float4*)(sbj + c0);
                float pv[4];
                pv[0] = vi.x * vj.x; pv[1] = vi.y * vj.y;
                pv[2] = vi.z * vj.z; pv[3] = vi.w * vj.w;
                #pragma unroll
                for (int q = 0; q < 4; ++q) {
                    int c = c0 + q;
                    float rm = rbb[c];
                    #pragma unroll
                    for (int k = 0; k < 8; ++k)
                        rm = fmaf(rbf[k], rwt[c*8 + k], rm);
                    float g = rm * pv[q] * chb;
                    const float* vc = vw + c*32;
                    #pragma unroll
                    for (int o = 0; o < 32; ++o)
                        s[o] = fmaf(vc[o], g, s[o]);
                }
            }
        }
        #pragma unroll
        for (int o = 0; o < 32; ++o) sall[w][o] = s[o];
    }

    // ---- Phase 2: 8 rounds of wave-local 1->8 transpose + epilogue ----
    const int g = lane >> 3;
    const int q = lane & 7;
    float* myslot = &hand[wv][lane & 7][0];
    const float* gslot = &hand[wv][g][0];
    float* myob = &obuf[wv][g][0];

    #pragma unroll 1
    for (int r = 0; r < 8; ++r) {
        if ((lane >> 3) == r) {
            #pragma unroll
            for (int w = 0; w < 3; ++w)
                #pragma unroll
                for (int k = 0; k < 8; ++k)
                    *(float4*)(myslot + w*32 + k*4) =
                        make_float4(sall[w][k*4+0], sall[w][k*4+1],
                                    sall[w][k*4+2], sall[w][k*4+3]);
            *(float4*)(myslot + 96) = make_float4(ux, uy, uz, 0.0f);
        }
        __builtin_amdgcn_wave_barrier();   // wave-level scheduling fence

        const int sl  = r*8 + g;
        const int e_r = __shfl(e, sl);
        const int j_r = __shfl(j, sl);

        float4 sv0 = *(const float4*)(gslot + 0  + q*4);
        float4 sv1 = *(const float4*)(gslot + 32 + q*4);
        float4 sv2 = *(const float4*)(gslot + 64 + q*4);
        float4 uu  = *(const float4*)(gslot + 96);
        float uxr = uu.x, uyr = uu.y, uzr = uu.z;
        float c0[4] = {sv0.x, sv0.y, sv0.z, sv0.w};
        float c1[4] = {sv1.x, sv1.y, sv1.z, sv1.w};
        float c2[4] = {sv2.x, sv2.y, sv2.z, sv2.w};

        const float* nmj = ws + NM_OFF + (size_t)j_r*512 + q*64;

        float r0[4], r1[12], r2[36];
        #pragma unroll
        for (int oo = 0; oo < 4; ++oo) {
            const float* nmo = nmj + oo*16;
            float4 va  = *(const float4*)(nmo + 0);
            float4 vb  = *(const float4*)(nmo + 4);
            float4 vc4 = *(const float4*)(nmo + 8);
            float nd   = nmo[12];
            float n0 = va.x, n1x = va.y, n1y = va.z, n1z = va.w;
            float t00 = vb.x, t01 = vb.y, t02 = vb.z, t10 = vb.w;
            float t11 = vc4.x, t12 = vc4.y, t20 = vc4.z, t21 = vc4.w, t22 = nd;
            float s0 = c0[oo], s1 = c1[oo], s2 = c2[oo];

            float d1 = n1x*uxr + n1y*uyr + n1z*uzr;
            float m0 = t00*uxr + t01*uyr + t02*uzr;
            float m1 = t10*uxr + t11*uyr + t12*uzr;
            float m2 = t20*uxr + t21*uyr + t22*uzr;
            float qq = m0*uxr + m1*uyr + m2*uzr;

            r0[oo] = n0*s0 + d1*s1 + qq*s2;

            float w1 = n0*s1 + s2*d1;
            r1[oo*3+0] = w1*uxr + n1x*s0 + s1*m0;
            r1[oo*3+1] = w1*uyr + n1y*s0 + s1*m1;
            r1[oo*3+2] = w1*uzr + n1z*s0 + s1*m2;

            float n0s2 = n0*s2;
            float a0 = uxr*n0s2 + s1*n1x + s2*m0;
            float a1 = uyr*n0s2 + s1*n1y + s2*m1;
            float a2 = uzr*n0s2 + s1*n1z + s2*m2;
            r2[oo*9+0] = a0*uxr + s0*t00;
            r2[oo*9+1] = a0*uyr + s0*t01;
            r2[oo*9+2] = a0*uzr + s0*t02;
            r2[oo*9+3] = a1*uxr + s0*t10;
            r2[oo*9+4] = a1*uyr + s0*t11;
            r2[oo*9+5] = a1*uzr + s0*t12;
            r2[oo*9+6] = a2*uxr + s0*t20;
            r2[oo*9+7] = a2*uyr + s0*t21;
            r2[oo*9+8] = a2*uzr + s0*t22;
        }

        // p2: direct stores (9-instruction tight burst combines in L2)
        float* p2 = out + (size_t)NE*128 + (size_t)e_r*288 + q*36;
        #pragma unroll
        for (int k = 0; k < 9; ++k)
            *(float4*)(p2 + k*4) =
                make_float4(r2[k*4+0], r2[k*4+1], r2[k*4+2], r2[k*4+3]);

        // p1/p0: stage in per-wave LDS (o-major layout = output layout)
        #pragma unroll
        for (int k = 0; k < 3; ++k)
            *(float4*)(myob + q*12 + k*4) =
                make_float4(r1[k*4+0], r1[k*4+1], r1[k*4+2], r1[k*4+3]);
        *(float4*)(myob + 96 + q*4) =
            make_float4(r0[0], r0[1], r0[2], r0[3]);
        __builtin_amdgcn_wave_barrier();

        // cooperative full-line store: group g streams edge-slot g's p1/p0;
        // each instruction = 8 lanes x 16B contiguous = one full 128B line.
        {
            const float* ob = &obuf[wv][g][0];
            float* d1 = out + (size_t)NE*32 + (size_t)e_r*96;
            #pragma unroll
            for (int k = 0; k < 3; ++k) {
                float4 v = *(const float4*)(ob + k*32 + q*4);
                *(float4*)(d1 + k*32 + q*4) = v;
            }
            float4 v0 = *(const float4*)(ob + 96 + q*4);
            *(float4*)(out + (size_t)e_r*32 + q*4) = v0;
        }

        __builtin_amdgcn_wave_barrier();   // keep next round's slot writes
                                           // behind this round's slot reads
    }
}

extern "C" void kernel_launch(void* const* d_in, const int* in_sizes, int n_in,
                              void* d_out, int out_size, void* d_ws, size_t ws_size,
                              hipStream_t stream) {
    const float* node0  = (const float*)d_in[0];
    const float* node1  = (const float*)d_in[1];
    const float* node2  = (const float*)d_in[2];
    const float* coord  = (const float*)d_in[3];
    const float* spin   = (const float*)d_in[4];
    const int*   idx_i  = (const int*)d_in[5];
    const int*   idx_j  = (const int*)d_in[6];
    const float* rbf_w  = (const float*)d_in[7];
    const float* rbf_b  = (const float*)d_in[8];
    const float* srbf_w = (const float*)d_in[9];
    const float* srbf_b = (const float*)d_in[10];
    const float* U_w    = (const float*)d_in[11];
    const float* V_w    = (const float*)d_in[12];
    float* out = (float*)d_out;
    float* ws  = (float*)d_ws;
    int*   wsi = (int*)d_ws;
    int*   hist = wsi + HIST_OFF;
    int*   perm = wsi + PERM_OFF;

    repack_rw_k<<<(2304 + 255) / 256, 256, 0, stream>>>(rbf_w, ws);
    atom_prep_k<<<NA / 4, 256, 0, stream>>>(node0, node1, node2, spin,
                                            srbf_w, srbf_b, U_w, ws);
    hist_zero_k<<<NA / 256, 256, 0, stream>>>(hist);
    hist_k<<<NE / 256, 256, 0, stream>>>(idx_j, hist);
    scan_k<<<1, 256, 0, stream>>>(hist);
    scatter_k<<<NE / 256, 256, 0, stream>>>(idx_j, hist, perm);
    edge_fused_k<<<NE / 256, 256, 0, stream>>>(coord, idx_i, idx_j, rbf_b,
                                               V_w, ws, perm, out);
}